// Round 1
// baseline (117.757 us; speedup 1.0000x reference)
//
#include <hip/hip_runtime.h>
#include <math.h>

#define D 256            // feature dim (D_IN == D_OUT == 256)
#define MAXNORM (1.0f - 4e-3f)   // (1 - BALL_EPS)/sqrt(c), c = 1
#define MIN_NORM 1e-15f

typedef _Float16 v8h __attribute__((ext_vector_type(8)));
typedef _Float16 h4  __attribute__((ext_vector_type(4)));
typedef float    v4f __attribute__((ext_vector_type(4)));

__device__ __forceinline__ float wave_reduce_sum(float v) {
    #pragma unroll
    for (int m = 32; m >= 1; m >>= 1) v += __shfl_xor(v, m, 64);
    return v;
}

__device__ __forceinline__ float dot4(const float4& a, const float4& b) {
    return a.x * b.x + a.y * b.y + a.z * b.z + a.w * b.w;
}

__device__ __forceinline__ float artanh_clip(float x) {
    x = fminf(fmaxf(x, -1.0f + 1e-7f), 1.0f - 1e-7f);
    return 0.5f * (log1pf(x) - log1pf(-x));
}

// ---------------------------------------------------------------------------
// Kernel 1 (prep): fuses
//   (a) rowptr fill from sorted adj_row          [all blocks, e < E]
//   (b) W fp32 -> fp16 cast                      [blocks 0..63]
//   (c) hyp_bias = proj(expmap0(bias)) + ||.||^2 [block 64, wave 0]
// ---------------------------------------------------------------------------
__global__ __launch_bounds__(256) void prep_kernel(
    const float* __restrict__ bias, const float* __restrict__ W,
    const int* __restrict__ rows,
    float* __restrict__ HB, _Float16* __restrict__ Wh,
    int* __restrict__ rowptr, int N, int E)
{
    const int b = blockIdx.x, t = threadIdx.x;
    const int e = b * 256 + t;

    if (e < E) {
        int r1 = rows[e];
        if (e == 0) {
            for (int r = 0; r <= r1; ++r) rowptr[r] = 0;
        } else {
            int r0 = rows[e - 1];
            for (int r = r0 + 1; r <= r1; ++r) rowptr[r] = e;
        }
        if (e == E - 1) {
            for (int r = r1 + 1; r <= N; ++r) rowptr[r] = E;
        }
    }

    if (b < 64) {   // W cast: 64 blocks x 256 threads x float4 = 65536 floats
        int i = b * 256 + t;
        float4 v = ((const float4*)W)[i];
        h4 o; o[0] = (_Float16)v.x; o[1] = (_Float16)v.y;
        o[2] = (_Float16)v.z; o[3] = (_Float16)v.w;
        *(h4*)(Wh + 4 * (size_t)i) = o;
    }

    if (b == 64 && t < 64) {   // bias (single wave)
        int l = t;
        float4 v = *(const float4*)(bias + 4 * l);
        float bn = fmaxf(sqrtf(wave_reduce_sum(dot4(v, v))), MIN_NORM);
        float f = tanhf(bn) / bn;
        float4 h = make_float4(v.x * f, v.y * f, v.z * f, v.w * f);
        float hn = fmaxf(sqrtf(wave_reduce_sum(dot4(h, h))), MIN_NORM);
        float s = (hn > MAXNORM) ? (MAXNORM / hn) : 1.0f;
        h.x *= s; h.y *= s; h.z *= s; h.w *= s;
        *(float4*)(HB + 4 * l) = h;
        float y2 = wave_reduce_sum(dot4(h, h));
        if (l == 0) HB[D] = y2;
    }
}

// ---------------------------------------------------------------------------
// Kernel 2 (fused GEMM + rowops): XT = rowops(X @ W^T) in one pass.
// (unchanged from previous round — see comments there)
// ---------------------------------------------------------------------------
#define AS16 264   // LDS row stride in halves (+8 pad)

__global__ __launch_bounds__(256) void gemmrow_kernel(
    const float* __restrict__ X, const _Float16* __restrict__ Wh,
    const float* __restrict__ HB, _Float16* __restrict__ XT, int N)
{
    __shared__ _Float16 As[16 * AS16];
    __shared__ float xnsq[16];
    __shared__ float part_s[16][4];
    __shared__ float part_d[16][4];
    __shared__ float Arow[16], Brow[16];

    const int t = threadIdx.x;
    const int r0 = blockIdx.x * 16;

    // ---- stage X rows [r0, r0+16) as fp16; per-row ||x||^2 in fp32 ----
    {
        const int r = t >> 4, q2 = t & 15;
        const int grow = r0 + r;
        float ss = 0.0f;
        #pragma unroll
        for (int j = 0; j < 4; ++j) {
            const int fi = q2 + j * 16;
            float4 v = make_float4(0.f, 0.f, 0.f, 0.f);
            if (grow < N) v = ((const float4*)X)[(size_t)grow * 64 + fi];
            ss += dot4(v, v);
            h4 hv; hv[0] = (_Float16)v.x; hv[1] = (_Float16)v.y;
            hv[2] = (_Float16)v.z; hv[3] = (_Float16)v.w;
            *(h4*)&As[r * AS16 + fi * 4] = hv;
        }
        ss += __shfl_xor(ss, 1, 64);
        ss += __shfl_xor(ss, 2, 64);
        ss += __shfl_xor(ss, 4, 64);
        ss += __shfl_xor(ss, 8, 64);
        if (q2 == 0) xnsq[r] = ss;
    }
    __syncthreads();

    // ---- MFMA: wave w computes rows 0..15 x cols [64w, 64w+64) ----
    const int w  = t >> 6;
    const int l  = t & 63;
    const int lm = l & 15;
    const int q  = l >> 4;

    v4f acc[4];
    #pragma unroll
    for (int ct = 0; ct < 4; ++ct)
        #pragma unroll
        for (int i = 0; i < 4; ++i) acc[ct][i] = 0.0f;

    const _Float16* WhB = Wh + (size_t)(64 * w + lm) * 256 + q * 8;

    #pragma unroll
    for (int kc = 0; kc < 8; ++kc) {
        v8h a = *(const v8h*)&As[lm * AS16 + kc * 32 + q * 8];
        #pragma unroll
        for (int ct = 0; ct < 4; ++ct) {
            v8h bfr = *(const v8h*)(WhB + (size_t)ct * 16 * 256 + kc * 32);
            acc[ct] = __builtin_amdgcn_mfma_f32_16x16x32_f16(a, bfr, acc[ct], 0, 0, 0);
        }
    }

    // y values for this lane's 4 columns
    float yv[4];
    #pragma unroll
    for (int ct = 0; ct < 4; ++ct) yv[ct] = HB[64 * w + ct * 16 + lm];

    // ---- per-row reductions: s = sum mx^2, d = <mx, y> (64 cols of wave w) ----
    {
        float s_[4], d_[4];
        #pragma unroll
        for (int i = 0; i < 4; ++i) {
            float s = 0.f, d = 0.f;
            #pragma unroll
            for (int ct = 0; ct < 4; ++ct) {
                float v = acc[ct][i];
                s = fmaf(v, v, s);
                d = fmaf(v, yv[ct], d);
            }
            #pragma unroll
            for (int m = 1; m <= 8; m <<= 1) {
                s += __shfl_xor(s, m, 64);
                d += __shfl_xor(d, m, 64);
            }
            s_[i] = s; d_[i] = d;
        }
        if (lm == 0) {
            #pragma unroll
            for (int i = 0; i < 4; ++i) {
                part_s[q * 4 + i][w] = s_[i];
                part_d[q * 4 + i][w] = d_[i];
            }
        }
    }
    __syncthreads();

    // ---- per-row scalar chain (exact rowops algebra, fp32) ----
    if (t < 16) {
        float mx2 = part_s[t][0] + part_s[t][1] + part_s[t][2] + part_s[t][3];
        float mxy = part_d[t][0] + part_d[t][1] + part_d[t][2] + part_d[t][3];
        float y2  = HB[D];
        float xn  = fmaxf(sqrtf(xnsq[t]), MIN_NORM);
        float mxn = fmaxf(sqrtf(mx2), MIN_NORM);
        // mobius_matvec tail: h = tanh(mxn/xn * artanh(xn)) * mx / mxn
        float r  = (mxn / xn) * artanh_clip(xn);
        float th = tanhf(r);              // = ||h|| before proj (>= 0)
        float f  = th / mxn;
        float hn = fmaxf(th, MIN_NORM);
        float s  = (hn > MAXNORM) ? (MAXNORM / hn) : 1.0f;
        float fs = f * s;                 // h = fs * mx
        float x2 = th * th * s * s;       // ||h||^2 after proj
        // mobius_add(h, y)
        float xy  = fs * mxy;
        float ch  = 1.0f + 2.0f * xy + y2;
        float cy  = 1.0f - x2;
        float inv = 1.0f / fmaxf(1.0f + 2.0f * xy + x2 * y2, MIN_NORM);
        float alpha = ch * fs * inv;      // g = alpha*mx + beta*y
        float beta  = cy * inv;
        // proj(g) + logmap0
        float gss = alpha * alpha * mx2 + 2.0f * alpha * beta * mxy + beta * beta * y2;
        float gn  = fmaxf(sqrtf(gss), MIN_NORM);
        float s2  = (gn > MAXNORM) ? (MAXNORM / gn) : 1.0f;
        float pn  = fmaxf(gn * s2, MIN_NORM);
        float lf  = artanh_clip(pn) / pn;
        Arow[t] = lf * s2 * alpha;
        Brow[t] = lf * s2 * beta;
    }
    __syncthreads();

    // ---- write XT = A*mx + B*y as fp16, straight from fragments ----
    #pragma unroll
    for (int i = 0; i < 4; ++i) {
        const int rr = q * 4 + i;
        const int row = r0 + rr;
        if (row < N) {
            float A = Arow[rr], B = Brow[rr];
            #pragma unroll
            for (int ct = 0; ct < 4; ++ct) {
                float v = fmaf(A, acc[ct][i], B * yv[ct]);
                XT[(size_t)row * 256 + 64 * w + ct * 16 + lm] = (_Float16)v;
            }
        }
    }
}

// ---------------------------------------------------------------------------
// Kernel 3: sparse aggregation (fp16 gather, fp32 accum) + HypAct
// One wave per node.  RESTRUCTURED gather:
//   - each gather instruction is 16B/lane (dwordx4) covering FOUR edges'
//     half-rows: sub-group g = lanes [16g,16g+16) reads 256B half-row of
//     edge j+4u+g, chunk ch = lane&15.
//   - 8 loads in flight = 32 edges / 8KB per wave (was 8 edges / 4KB),
//     2x fewer gather instrs per byte, 4x fewer bpermute broadcasts/edge.
//   - features split in halves A (0..127) and B (128..255); lane owns 8+8.
//   - epilogue: ||h|| = f*||acc|| and ||o|| = f2*||tt|| computed
//     algebraically (drops 2 of 4 wave reductions); remaining reductions
//     are 4-step (16-lane periodic ownership).
// ---------------------------------------------------------------------------
__global__ __launch_bounds__(256) void agg_kernel(
    const int* __restrict__ rowptr, const int* __restrict__ cols,
    const float* __restrict__ vals, const _Float16* __restrict__ XT,
    float* __restrict__ OUT, int N)
{
    int node = (int)((blockIdx.x * (size_t)blockDim.x + threadIdx.x) >> 6);
    int l = threadIdx.x & 63;
    if (node >= N) return;

    int start = rowptr[node];
    int end   = rowptr[node + 1];

    const int sub = l >> 4;        // which edge of the 4-group this lane serves
    const int ch  = l & 15;        // 16B chunk within the 256B half-row

    const v8h* xt8 = (const v8h*)XT;   // row = 32 chunks of 8 halves (16B)

    float accA[8] = {0.f,0.f,0.f,0.f,0.f,0.f,0.f,0.f};
    float accB[8] = {0.f,0.f,0.f,0.f,0.f,0.f,0.f,0.f};

    for (int base = start; base < end; base += 64) {
        int idx = base + l;
        bool ok = idx < end;
        int   myc = ok ? cols[idx] : 0;
        float myv = ok ? vals[idx] : 0.0f;
        int cnt = min(64, end - base);
        int cnt32 = (cnt + 31) & ~31;   // pad to 32; padded lanes v=0, c=0

        for (int j = 0; j < cnt32; j += 32) {
            int   c[8];
            float v[8];
            #pragma unroll
            for (int u = 0; u < 8; ++u) {
                c[u] = __shfl(myc, j + 4 * u + sub, 64);
                v[u] = __shfl(myv, j + 4 * u + sub, 64);
            }
            v8h m[8];
            // half A: chunks 0..15 (features 0..127)
            #pragma unroll
            for (int u = 0; u < 8; ++u)
                m[u] = xt8[(size_t)c[u] * 32 + ch];
            #pragma unroll
            for (int u = 0; u < 8; ++u) {
                #pragma unroll
                for (int k = 0; k < 8; ++k)
                    accA[k] = fmaf(v[u], (float)m[u][k], accA[k]);
            }
            // half B: chunks 16..31 (features 128..255)
            #pragma unroll
            for (int u = 0; u < 8; ++u)
                m[u] = xt8[(size_t)c[u] * 32 + 16 + ch];
            #pragma unroll
            for (int u = 0; u < 8; ++u) {
                #pragma unroll
                for (int k = 0; k < 8; ++k)
                    accB[k] = fmaf(v[u], (float)m[u][k], accB[k]);
            }
        }
    }

    // ---- combine the 4 edge sub-groups: lanes l, l^16, l^32, l^48 hold
    //      partial sums of the SAME features over disjoint edge sets ----
    #pragma unroll
    for (int k = 0; k < 8; ++k) {
        accA[k] += __shfl_xor(accA[k], 16, 64);
        accA[k] += __shfl_xor(accA[k], 32, 64);
        accB[k] += __shfl_xor(accB[k], 16, 64);
        accB[k] += __shfl_xor(accB[k], 32, 64);
    }

    // ---- ||acc||^2: each 16-lane group holds the full 256 features ----
    float ss = 0.f;
    #pragma unroll
    for (int k = 0; k < 8; ++k) ss += accA[k]*accA[k] + accB[k]*accB[k];
    #pragma unroll
    for (int mk = 1; mk <= 8; mk <<= 1) ss += __shfl_xor(ss, mk, 64);

    // expmap0 + proj  (||h|| = f * un algebraically)
    float un = fmaxf(sqrtf(ss), MIN_NORM);
    float f  = tanhf(un) / un;
    float hn = f * un;
    float s  = (hn > MAXNORM) ? (MAXNORM / hn) : 1.0f;
    // logmap0 + relu   (tt = relu(acc * f*s * lf))
    float pn = fmaxf(hn * s, MIN_NORM);
    float lf = artanh_clip(pn) / pn;
    float g  = f * s * lf;
    float tA[8], tB[8];
    float ss2 = 0.f;
    #pragma unroll
    for (int k = 0; k < 8; ++k) {
        tA[k] = fmaxf(accA[k] * g, 0.f);
        tB[k] = fmaxf(accB[k] * g, 0.f);
        ss2 += tA[k]*tA[k] + tB[k]*tB[k];
    }
    #pragma unroll
    for (int mk = 1; mk <= 8; mk <<= 1) ss2 += __shfl_xor(ss2, mk, 64);

    // expmap0 (c_out=1) + proj  (||o|| = f2 * un2 algebraically)
    float un2 = fmaxf(sqrtf(ss2), MIN_NORM);
    float f2  = tanhf(un2) / un2;
    float on  = f2 * un2;
    float s2  = (on > MAXNORM) ? (MAXNORM / on) : 1.0f;
    float fo  = f2 * s2;

    // ---- write: quad q writes its float4; 64 lanes cover the 256 feats ----
    const int q = sub;
    int off = (q >> 1) * 128 + ch * 8 + (q & 1) * 4;
    float4 wv;
    if (q == 0)      wv = make_float4(tA[0]*fo, tA[1]*fo, tA[2]*fo, tA[3]*fo);
    else if (q == 1) wv = make_float4(tA[4]*fo, tA[5]*fo, tA[6]*fo, tA[7]*fo);
    else if (q == 2) wv = make_float4(tB[0]*fo, tB[1]*fo, tB[2]*fo, tB[3]*fo);
    else             wv = make_float4(tB[4]*fo, tB[5]*fo, tB[6]*fo, tB[7]*fo);
    *(float4*)(OUT + (size_t)node * D + off) = wv;
}

// ---------------------------------------------------------------------------
extern "C" void kernel_launch(void* const* d_in, const int* in_sizes, int n_in,
                              void* d_out, int out_size, void* d_ws, size_t ws_size,
                              hipStream_t stream) {
    const float* X    = (const float*)d_in[0];
    const float* W    = (const float*)d_in[1];
    const float* bias = (const float*)d_in[2];
    const float* vals = (const float*)d_in[3];
    const int*   rows = (const int*)d_in[4];
    const int*   cols = (const int*)d_in[5];
    float* OUT = (float*)d_out;

    const int N = in_sizes[0] / D;   // 10000
    const int E = in_sizes[3];       // 320000

    // ws layout (float units): rowptr [10240] | HB [512] | Wh [32768] | XT [...]
    int*      rowptr = (int*)d_ws;
    float*    HB = (float*)d_ws + 10240;
    _Float16* Wh = (_Float16*)((float*)d_ws + 10240 + 512);
    _Float16* XT = (_Float16*)((float*)d_ws + 10240 + 512 + 32768);

    prep_kernel<<<(E + 255) / 256, 256, 0, stream>>>(bias, W, rows, HB, Wh, rowptr, N, E);
    gemmrow_kernel<<<(N + 15) / 16, 256, 0, stream>>>(X, Wh, HB, XT, N);
    int wave_blocks = (N + 3) / 4;   // 4 waves per 256-thread block
    agg_kernel<<<wave_blocks, 256, 0, stream>>>(rowptr, cols, vals, XT, OUT, N);
}

// Round 3
// 108.316 us; speedup vs baseline: 1.0872x; 1.0872x over previous
//
#include <hip/hip_runtime.h>
#include <math.h>

#define D 256            // feature dim (D_IN == D_OUT == 256)
#define MAXNORM (1.0f - 4e-3f)   // (1 - BALL_EPS)/sqrt(c), c = 1
#define MIN_NORM 1e-15f

typedef _Float16 v8h __attribute__((ext_vector_type(8)));
typedef _Float16 h4  __attribute__((ext_vector_type(4)));
typedef float    v4f __attribute__((ext_vector_type(4)));

__device__ __forceinline__ float wave_reduce_sum(float v) {
    #pragma unroll
    for (int m = 32; m >= 1; m >>= 1) v += __shfl_xor(v, m, 64);
    return v;
}

__device__ __forceinline__ float dot4(const float4& a, const float4& b) {
    return a.x * b.x + a.y * b.y + a.z * b.z + a.w * b.w;
}

__device__ __forceinline__ float artanh_clip(float x) {
    x = fminf(fmaxf(x, -1.0f + 1e-7f), 1.0f - 1e-7f);
    return 0.5f * (log1pf(x) - log1pf(-x));
}

// ---------------------------------------------------------------------------
// Kernel 1 (prep): rowptr fill + W fp32->fp16 cast + hyp_bias. (unchanged)
// ---------------------------------------------------------------------------
__global__ __launch_bounds__(256) void prep_kernel(
    const float* __restrict__ bias, const float* __restrict__ W,
    const int* __restrict__ rows,
    float* __restrict__ HB, _Float16* __restrict__ Wh,
    int* __restrict__ rowptr, int N, int E)
{
    const int b = blockIdx.x, t = threadIdx.x;
    const int e = b * 256 + t;

    if (e < E) {
        int r1 = rows[e];
        if (e == 0) {
            for (int r = 0; r <= r1; ++r) rowptr[r] = 0;
        } else {
            int r0 = rows[e - 1];
            for (int r = r0 + 1; r <= r1; ++r) rowptr[r] = e;
        }
        if (e == E - 1) {
            for (int r = r1 + 1; r <= N; ++r) rowptr[r] = E;
        }
    }

    if (b < 64) {   // W cast: 64 blocks x 256 threads x float4 = 65536 floats
        int i = b * 256 + t;
        float4 v = ((const float4*)W)[i];
        h4 o; o[0] = (_Float16)v.x; o[1] = (_Float16)v.y;
        o[2] = (_Float16)v.z; o[3] = (_Float16)v.w;
        *(h4*)(Wh + 4 * (size_t)i) = o;
    }

    if (b == 64 && t < 64) {   // bias (single wave)
        int l = t;
        float4 v = *(const float4*)(bias + 4 * l);
        float bn = fmaxf(sqrtf(wave_reduce_sum(dot4(v, v))), MIN_NORM);
        float f = tanhf(bn) / bn;
        float4 h = make_float4(v.x * f, v.y * f, v.z * f, v.w * f);
        float hn = fmaxf(sqrtf(wave_reduce_sum(dot4(h, h))), MIN_NORM);
        float s = (hn > MAXNORM) ? (MAXNORM / hn) : 1.0f;
        h.x *= s; h.y *= s; h.z *= s; h.w *= s;
        *(float4*)(HB + 4 * l) = h;
        float y2 = wave_reduce_sum(dot4(h, h));
        if (l == 0) HB[D] = y2;
    }
}

// ---------------------------------------------------------------------------
// Kernel 2 (fused GEMM + rowops): XT8 = int8(rowops(X @ W^T)), biased uint8
// with per-row linear scale: q = rint(xt * 127/rowmax) + 128,
// dequant xt ~= (q - 128) * SCg[row],  SCg = rowmax/127.
// Body unchanged through the scalar chain; epilogue:
//   pass1: per-row max|xt| (shfl + LDS reduce)  -> Srow = 127/rowmax
//   pass2: encode into LDS staging [16][256] -> coalesced uint4 writes
// ---------------------------------------------------------------------------
#define AS16 264   // LDS row stride in halves (+8 pad)

__global__ __launch_bounds__(256) void gemmrow_kernel(
    const float* __restrict__ X, const _Float16* __restrict__ Wh,
    const float* __restrict__ HB, unsigned char* __restrict__ XT8,
    float* __restrict__ SCg, int N)
{
    __shared__ _Float16 As[16 * AS16];
    __shared__ float xnsq[16];
    __shared__ float part_s[16][4];
    __shared__ float part_d[16][4];
    __shared__ float Arow[16], Brow[16];
    __shared__ float pmax[16][4];
    __shared__ float Srow[16];
    __shared__ unsigned char stage[16 * 256];

    const int t = threadIdx.x;
    const int r0 = blockIdx.x * 16;

    // ---- stage X rows [r0, r0+16) as fp16; per-row ||x||^2 in fp32 ----
    {
        const int r = t >> 4, q2 = t & 15;
        const int grow = r0 + r;
        float ss = 0.0f;
        #pragma unroll
        for (int j = 0; j < 4; ++j) {
            const int fi = q2 + j * 16;
            float4 v = make_float4(0.f, 0.f, 0.f, 0.f);
            if (grow < N) v = ((const float4*)X)[(size_t)grow * 64 + fi];
            ss += dot4(v, v);
            h4 hv; hv[0] = (_Float16)v.x; hv[1] = (_Float16)v.y;
            hv[2] = (_Float16)v.z; hv[3] = (_Float16)v.w;
            *(h4*)&As[r * AS16 + fi * 4] = hv;
        }
        ss += __shfl_xor(ss, 1, 64);
        ss += __shfl_xor(ss, 2, 64);
        ss += __shfl_xor(ss, 4, 64);
        ss += __shfl_xor(ss, 8, 64);
        if (q2 == 0) xnsq[r] = ss;
    }
    __syncthreads();

    // ---- MFMA: wave w computes rows 0..15 x cols [64w, 64w+64) ----
    const int w  = t >> 6;
    const int l  = t & 63;
    const int lm = l & 15;
    const int q  = l >> 4;

    v4f acc[4];
    #pragma unroll
    for (int ct = 0; ct < 4; ++ct)
        #pragma unroll
        for (int i = 0; i < 4; ++i) acc[ct][i] = 0.0f;

    const _Float16* WhB = Wh + (size_t)(64 * w + lm) * 256 + q * 8;

    #pragma unroll
    for (int kc = 0; kc < 8; ++kc) {
        v8h a = *(const v8h*)&As[lm * AS16 + kc * 32 + q * 8];
        #pragma unroll
        for (int ct = 0; ct < 4; ++ct) {
            v8h bfr = *(const v8h*)(WhB + (size_t)ct * 16 * 256 + kc * 32);
            acc[ct] = __builtin_amdgcn_mfma_f32_16x16x32_f16(a, bfr, acc[ct], 0, 0, 0);
        }
    }

    // y values for this lane's 4 columns
    float yv[4];
    #pragma unroll
    for (int ct = 0; ct < 4; ++ct) yv[ct] = HB[64 * w + ct * 16 + lm];

    // ---- per-row reductions: s = sum mx^2, d = <mx, y> ----
    {
        float s_[4], d_[4];
        #pragma unroll
        for (int i = 0; i < 4; ++i) {
            float s = 0.f, d = 0.f;
            #pragma unroll
            for (int ct = 0; ct < 4; ++ct) {
                float v = acc[ct][i];
                s = fmaf(v, v, s);
                d = fmaf(v, yv[ct], d);
            }
            #pragma unroll
            for (int m = 1; m <= 8; m <<= 1) {
                s += __shfl_xor(s, m, 64);
                d += __shfl_xor(d, m, 64);
            }
            s_[i] = s; d_[i] = d;
        }
        if (lm == 0) {
            #pragma unroll
            for (int i = 0; i < 4; ++i) {
                part_s[q * 4 + i][w] = s_[i];
                part_d[q * 4 + i][w] = d_[i];
            }
        }
    }
    __syncthreads();

    // ---- per-row scalar chain (exact rowops algebra, fp32) ----
    if (t < 16) {
        float mx2 = part_s[t][0] + part_s[t][1] + part_s[t][2] + part_s[t][3];
        float mxy = part_d[t][0] + part_d[t][1] + part_d[t][2] + part_d[t][3];
        float y2  = HB[D];
        float xn  = fmaxf(sqrtf(xnsq[t]), MIN_NORM);
        float mxn = fmaxf(sqrtf(mx2), MIN_NORM);
        float r  = (mxn / xn) * artanh_clip(xn);
        float th = tanhf(r);
        float f  = th / mxn;
        float hn = fmaxf(th, MIN_NORM);
        float s  = (hn > MAXNORM) ? (MAXNORM / hn) : 1.0f;
        float fs = f * s;
        float x2 = th * th * s * s;
        float xy  = fs * mxy;
        float ch  = 1.0f + 2.0f * xy + y2;
        float cy  = 1.0f - x2;
        float inv = 1.0f / fmaxf(1.0f + 2.0f * xy + x2 * y2, MIN_NORM);
        float alpha = ch * fs * inv;
        float beta  = cy * inv;
        float gss = alpha * alpha * mx2 + 2.0f * alpha * beta * mxy + beta * beta * y2;
        float gn  = fmaxf(sqrtf(gss), MIN_NORM);
        float s2  = (gn > MAXNORM) ? (MAXNORM / gn) : 1.0f;
        float pn  = fmaxf(gn * s2, MIN_NORM);
        float lf  = artanh_clip(pn) / pn;
        Arow[t] = lf * s2 * alpha;
        Brow[t] = lf * s2 * beta;
    }
    __syncthreads();

    // ---- pass 1: per-row max |xt| over this wave's 64 cols, then block ----
    {
        float vmax[4];
        #pragma unroll
        for (int i = 0; i < 4; ++i) {
            const int rr = q * 4 + i;
            float A = Arow[rr], B = Brow[rr];
            float m = 0.f;
            #pragma unroll
            for (int ct = 0; ct < 4; ++ct)
                m = fmaxf(m, fabsf(fmaf(A, acc[ct][i], B * yv[ct])));
            #pragma unroll
            for (int mk = 1; mk <= 8; mk <<= 1)
                m = fmaxf(m, __shfl_xor(m, mk, 64));
            vmax[i] = m;
        }
        if (lm == 0) {
            #pragma unroll
            for (int i = 0; i < 4; ++i) pmax[q * 4 + i][w] = vmax[i];
        }
    }
    __syncthreads();
    if (t < 16) {
        float rm = fmaxf(fmaxf(pmax[t][0], pmax[t][1]),
                         fmaxf(pmax[t][2], pmax[t][3]));
        Srow[t] = 127.0f / fmaxf(rm, 1e-30f);
        if (r0 + t < N) SCg[r0 + t] = rm * (1.0f / 127.0f);
    }
    __syncthreads();

    // ---- pass 2: encode (rint(xt*S)+128) into LDS staging, coalesced out ----
    #pragma unroll
    for (int i = 0; i < 4; ++i) {
        const int rr = q * 4 + i;
        float A = Arow[rr], B = Brow[rr], S = Srow[rr];
        #pragma unroll
        for (int ct = 0; ct < 4; ++ct) {
            float v = fmaf(A, acc[ct][i], B * yv[ct]) * S;   // in [-127, 127]
            v = fminf(fmaxf(v, -127.0f), 127.0f);
            int qi = (int)rintf(v) + 128;                    // [1, 255]
            stage[rr * 256 + 64 * w + ct * 16 + lm] = (unsigned char)qi;
        }
    }
    __syncthreads();
    {
        const int rr2 = t >> 4, seg = t & 15;   // 16 B per thread
        if (r0 + rr2 < N)
            *(uint4*)(XT8 + (size_t)(r0 + rr2) * 256 + seg * 16) =
                *(const uint4*)&stage[rr2 * 256 + seg * 16];
    }
}

// ---------------------------------------------------------------------------
// Kernel 3: sparse aggregation (int8 gather, fp32 accum) + HypAct.
// One wave per node, shfl-broadcast cols/weights, 16-deep pipelined dword
// gathers (one 256 B row per instruction = 2 cache lines, half of fp16's 4).
// Dequant: xt = (q - 128) * SCg[row]; SCg folded into edge weight, the -128
// bias handled exactly via the running weight-sum:
//   acc_f = sum_e w'_e q_{e,f} - 128 * sum_e w'_e
// ---------------------------------------------------------------------------
__global__ __launch_bounds__(256) void agg_kernel(
    const int* __restrict__ rowptr, const int* __restrict__ cols,
    const float* __restrict__ vals, const float* __restrict__ SCg,
    const unsigned int* __restrict__ XT8u,
    float* __restrict__ OUT, int N)
{
    int node = (int)((blockIdx.x * (size_t)blockDim.x + threadIdx.x) >> 6);
    int l = threadIdx.x & 63;
    if (node >= N) return;

    int start = rowptr[node];
    int end   = rowptr[node + 1];

    float4 acc = make_float4(0.f, 0.f, 0.f, 0.f);
    float sw = 0.0f;   // sum of folded edge weights (identical across lanes)

    for (int base = start; base < end; base += 64) {
        int idx = base + l;
        bool ok = idx < end;
        int   myc = ok ? cols[idx] : 0;
        float myv = ok ? vals[idx] * SCg[myc] : 0.0f;   // fold dequant scale
        int cnt = min(64, end - base);
        int cnt16 = (cnt + 15) & ~15;   // pad to 16; padded lanes v=0, c=0 (hot line)

        for (int j = 0; j < cnt16; j += 16) {
            int   cc[16];
            float ww[16];
            #pragma unroll
            for (int u = 0; u < 16; ++u) {
                cc[u] = __shfl(myc, j + u, 64);
                ww[u] = __shfl(myv, j + u, 64);
            }
            unsigned int mw[16];
            #pragma unroll
            for (int u = 0; u < 16; ++u)
                mw[u] = XT8u[(size_t)cc[u] * 64 + l];   // 4 B/lane = 256 B row
            #pragma unroll
            for (int u = 0; u < 16; ++u) {
                float f0 = (float)( mw[u]        & 0xffu);   // v_cvt_f32_ubyte0
                float f1 = (float)((mw[u] >> 8)  & 0xffu);
                float f2 = (float)((mw[u] >> 16) & 0xffu);
                float f3 = (float)( mw[u] >> 24);
                acc.x = fmaf(ww[u], f0, acc.x);
                acc.y = fmaf(ww[u], f1, acc.y);
                acc.z = fmaf(ww[u], f2, acc.z);
                acc.w = fmaf(ww[u], f3, acc.w);
                sw += ww[u];
            }
        }
    }

    // exact -128 bias correction
    float corr = 128.0f * sw;
    acc.x -= corr; acc.y -= corr; acc.z -= corr; acc.w -= corr;

    // expmap0
    float un = fmaxf(sqrtf(wave_reduce_sum(dot4(acc, acc))), MIN_NORM);
    float f = tanhf(un) / un;
    float4 h = make_float4(acc.x * f, acc.y * f, acc.z * f, acc.w * f);
    // proj
    float hn = fmaxf(sqrtf(wave_reduce_sum(dot4(h, h))), MIN_NORM);
    float s = (hn > MAXNORM) ? (MAXNORM / hn) : 1.0f;
    h.x *= s; h.y *= s; h.z *= s; h.w *= s;
    // logmap0 + relu
    float pn = fmaxf(hn * s, MIN_NORM);
    float lf = artanh_clip(pn) / pn;
    float4 tt = make_float4(fmaxf(h.x * lf, 0.f), fmaxf(h.y * lf, 0.f),
                            fmaxf(h.z * lf, 0.f), fmaxf(h.w * lf, 0.f));
    // expmap0 (c_out = 1)
    float un2 = fmaxf(sqrtf(wave_reduce_sum(dot4(tt, tt))), MIN_NORM);
    float f2 = tanhf(un2) / un2;
    float4 o = make_float4(tt.x * f2, tt.y * f2, tt.z * f2, tt.w * f2);
    // proj
    float on = fmaxf(sqrtf(wave_reduce_sum(dot4(o, o))), MIN_NORM);
    float s2 = (on > MAXNORM) ? (MAXNORM / on) : 1.0f;
    o.x *= s2; o.y *= s2; o.z *= s2; o.w *= s2;

    *(float4*)(OUT + (size_t)node * D + 4 * l) = o;
}

// ---------------------------------------------------------------------------
extern "C" void kernel_launch(void* const* d_in, const int* in_sizes, int n_in,
                              void* d_out, int out_size, void* d_ws, size_t ws_size,
                              hipStream_t stream) {
    const float* X    = (const float*)d_in[0];
    const float* W    = (const float*)d_in[1];
    const float* bias = (const float*)d_in[2];
    const float* vals = (const float*)d_in[3];
    const int*   rows = (const int*)d_in[4];
    const int*   cols = (const int*)d_in[5];
    float* OUT = (float*)d_out;

    const int N = in_sizes[0] / D;   // 10000
    const int E = in_sizes[3];       // 320000

    // ws layout (float units):
    //   rowptr [10240] | HB [512] | Wh [32768] | SCg [10240] | XT8 [...]
    int*           rowptr = (int*)d_ws;
    float*         HB  = (float*)d_ws + 10240;
    _Float16*      Wh  = (_Float16*)((float*)d_ws + 10240 + 512);
    float*         SCg = (float*)d_ws + 10240 + 512 + 32768;
    unsigned char* XT8 = (unsigned char*)((float*)d_ws + 10240 + 512 + 32768 + 10240);

    prep_kernel<<<(E + 255) / 256, 256, 0, stream>>>(bias, W, rows, HB, Wh, rowptr, N, E);
    gemmrow_kernel<<<(N + 15) / 16, 256, 0, stream>>>(X, Wh, HB, XT8, SCg, N);
    int wave_blocks = (N + 3) / 4;   // 4 waves per 256-thread block
    agg_kernel<<<wave_blocks, 256, 0, stream>>>(rowptr, cols, vals, SCg,
                                                (const unsigned int*)XT8, OUT, N);
}

// Round 4
// 101.388 us; speedup vs baseline: 1.1614x; 1.0683x over previous
//
#include <hip/hip_runtime.h>
#include <math.h>

#define D 256            // feature dim (D_IN == D_OUT == 256)
#define MAXNORM (1.0f - 4e-3f)   // (1 - BALL_EPS)/sqrt(c), c = 1
#define MIN_NORM 1e-15f

typedef _Float16 v8h __attribute__((ext_vector_type(8)));
typedef _Float16 h4  __attribute__((ext_vector_type(4)));
typedef float    v4f __attribute__((ext_vector_type(4)));

__device__ __forceinline__ float wave_reduce_sum(float v) {
    #pragma unroll
    for (int m = 32; m >= 1; m >>= 1) v += __shfl_xor(v, m, 64);
    return v;
}

__device__ __forceinline__ float dot4(const float4& a, const float4& b) {
    return a.x * b.x + a.y * b.y + a.z * b.z + a.w * b.w;
}

__device__ __forceinline__ float artanh_clip(float x) {
    x = fminf(fmaxf(x, -1.0f + 1e-7f), 1.0f - 1e-7f);
    return 0.5f * (log1pf(x) - log1pf(-x));
}

// ---------------------------------------------------------------------------
// Kernel 1 (prep): rowptr fill + W fp32->fp16 cast into SWIZZLED layout +
// hyp_bias.  Swizzle: chunk j in [0,8192) of 16 B holds
//   col = wc*64 + ct*16 + (l&15),  k = kc*32 + ((l>>4)&3)*8 .. +7
// where j = ((wc*4+ct)*8 + kc)*64 + l.  This makes gemmrow's B-fragment
// load (64 lanes x 16 B) one CONTIGUOUS 1 KiB block (8 cache lines instead
// of 16 rows x 512B-strided pieces).
// ---------------------------------------------------------------------------
__global__ __launch_bounds__(256) void prep_kernel(
    const float* __restrict__ bias, const float* __restrict__ W,
    const int* __restrict__ rows,
    float* __restrict__ HB, _Float16* __restrict__ Wh,
    int* __restrict__ rowptr, int N, int E)
{
    const int b = blockIdx.x, t = threadIdx.x;
    const int e = b * 256 + t;

    if (e < E) {
        int r1 = rows[e];
        if (e == 0) {
            for (int r = 0; r <= r1; ++r) rowptr[r] = 0;
        } else {
            int r0 = rows[e - 1];
            for (int r = r0 + 1; r <= r1; ++r) rowptr[r] = e;
        }
        if (e == E - 1) {
            for (int r = r1 + 1; r <= N; ++r) rowptr[r] = E;
        }
    }

    if (b < 32) {   // swizzled W cast: 8192 chunks x 16 B
        int j  = b * 256 + t;
        int l  = j & 63;
        int g  = j >> 6;            // [0,128)
        int kc = g & 7;
        int ct = (g >> 3) & 3;
        int wc = g >> 5;
        int col = wc * 64 + ct * 16 + (l & 15);
        int kb  = kc * 32 + ((l >> 4) & 3) * 8;
        const float* src = W + (size_t)col * 256 + kb;
        float4 v0 = *(const float4*)src;
        float4 v1 = *(const float4*)(src + 4);
        v8h o;
        o[0] = (_Float16)v0.x; o[1] = (_Float16)v0.y;
        o[2] = (_Float16)v0.z; o[3] = (_Float16)v0.w;
        o[4] = (_Float16)v1.x; o[5] = (_Float16)v1.y;
        o[6] = (_Float16)v1.z; o[7] = (_Float16)v1.w;
        *(v8h*)(Wh + (size_t)j * 8) = o;
    }

    if (b == 64 && t < 64) {   // bias (single wave)
        int l = t;
        float4 v = *(const float4*)(bias + 4 * l);
        float bn = fmaxf(sqrtf(wave_reduce_sum(dot4(v, v))), MIN_NORM);
        float f = tanhf(bn) / bn;
        float4 h = make_float4(v.x * f, v.y * f, v.z * f, v.w * f);
        float hn = fmaxf(sqrtf(wave_reduce_sum(dot4(h, h))), MIN_NORM);
        float s = (hn > MAXNORM) ? (MAXNORM / hn) : 1.0f;
        h.x *= s; h.y *= s; h.z *= s; h.w *= s;
        *(float4*)(HB + 4 * l) = h;
        float y2 = wave_reduce_sum(dot4(h, h));
        if (l == 0) HB[D] = y2;
    }
}

// ---------------------------------------------------------------------------
// Kernel 2 (fused GEMM + rowops): 32 rows x 256 cols per block, 8 waves.
// Wave wv: row-half rh = wv>>2 (rows rh*16..+15), col-group wc = wv&3
// (cols 64*wc..+63).  B-fragments from swizzled Wh: contiguous 1 KiB/load.
// Output: XT8 = biased-uint8 per-row linear quant (R3, verified).
// ---------------------------------------------------------------------------
#define AS16 264   // LDS row stride in halves (+8 pad)

__global__ __launch_bounds__(512) void gemmrow_kernel(
    const float* __restrict__ X, const _Float16* __restrict__ Wh,
    const float* __restrict__ HB, unsigned char* __restrict__ XT8,
    float* __restrict__ SCg, int N)
{
    __shared__ _Float16 As[32 * AS16];
    __shared__ float xnsq[32];
    __shared__ float part_s[32][4];
    __shared__ float part_d[32][4];
    __shared__ float Arow[32], Brow[32];
    __shared__ float pmax[32][4];
    __shared__ float Srow[32];
    __shared__ unsigned char stage[32 * 256];

    const int t = threadIdx.x;
    const int r0 = blockIdx.x * 32;

    // ---- stage X rows [r0, r0+32) as fp16; per-row ||x||^2 in fp32 ----
    {
        const int r = t >> 4, q2 = t & 15;   // r in [0,32)
        const int grow = r0 + r;
        float ss = 0.0f;
        #pragma unroll
        for (int j = 0; j < 4; ++j) {
            const int fi = q2 + j * 16;
            float4 v = make_float4(0.f, 0.f, 0.f, 0.f);
            if (grow < N) v = ((const float4*)X)[(size_t)grow * 64 + fi];
            ss += dot4(v, v);
            h4 hv; hv[0] = (_Float16)v.x; hv[1] = (_Float16)v.y;
            hv[2] = (_Float16)v.z; hv[3] = (_Float16)v.w;
            *(h4*)&As[r * AS16 + fi * 4] = hv;
        }
        ss += __shfl_xor(ss, 1, 64);
        ss += __shfl_xor(ss, 2, 64);
        ss += __shfl_xor(ss, 4, 64);
        ss += __shfl_xor(ss, 8, 64);
        if (q2 == 0) xnsq[r] = ss;
    }
    __syncthreads();

    // ---- MFMA: wave wv computes rows [rh*16, rh*16+16) x cols [64wc, +64) ----
    const int wv = t >> 6;
    const int rh = wv >> 2;
    const int wc = wv & 3;
    const int l  = t & 63;
    const int lm = l & 15;
    const int q  = l >> 4;

    v4f acc[4];
    #pragma unroll
    for (int ct = 0; ct < 4; ++ct)
        #pragma unroll
        for (int i = 0; i < 4; ++i) acc[ct][i] = 0.0f;

    #pragma unroll
    for (int kc = 0; kc < 8; ++kc) {
        v8h a = *(const v8h*)&As[(rh * 16 + lm) * AS16 + kc * 32 + q * 8];
        #pragma unroll
        for (int ct = 0; ct < 4; ++ct) {
            // swizzled: chunk (wc*32 + ct*8 + kc)*64 + l, 16 B each -> 1 KiB
            v8h bfr = *(const v8h*)(Wh +
                (((size_t)(wc * 32 + ct * 8 + kc) * 64 + l) * 8));
            acc[ct] = __builtin_amdgcn_mfma_f32_16x16x32_f16(a, bfr, acc[ct], 0, 0, 0);
        }
    }

    // y values for this lane's 4 columns
    float yv[4];
    #pragma unroll
    for (int ct = 0; ct < 4; ++ct) yv[ct] = HB[64 * wc + ct * 16 + lm];

    // ---- per-row reductions: s = sum mx^2, d = <mx, y> ----
    {
        float s_[4], d_[4];
        #pragma unroll
        for (int i = 0; i < 4; ++i) {
            float s = 0.f, d = 0.f;
            #pragma unroll
            for (int ct = 0; ct < 4; ++ct) {
                float v = acc[ct][i];
                s = fmaf(v, v, s);
                d = fmaf(v, yv[ct], d);
            }
            #pragma unroll
            for (int m = 1; m <= 8; m <<= 1) {
                s += __shfl_xor(s, m, 64);
                d += __shfl_xor(d, m, 64);
            }
            s_[i] = s; d_[i] = d;
        }
        if (lm == 0) {
            #pragma unroll
            for (int i = 0; i < 4; ++i) {
                part_s[rh * 16 + q * 4 + i][wc] = s_[i];
                part_d[rh * 16 + q * 4 + i][wc] = d_[i];
            }
        }
    }
    __syncthreads();

    // ---- per-row scalar chain (exact rowops algebra, fp32) ----
    if (t < 32) {
        float mx2 = part_s[t][0] + part_s[t][1] + part_s[t][2] + part_s[t][3];
        float mxy = part_d[t][0] + part_d[t][1] + part_d[t][2] + part_d[t][3];
        float y2  = HB[D];
        float xn  = fmaxf(sqrtf(xnsq[t]), MIN_NORM);
        float mxn = fmaxf(sqrtf(mx2), MIN_NORM);
        float r  = (mxn / xn) * artanh_clip(xn);
        float th = tanhf(r);
        float f  = th / mxn;
        float hn = fmaxf(th, MIN_NORM);
        float s  = (hn > MAXNORM) ? (MAXNORM / hn) : 1.0f;
        float fs = f * s;
        float x2 = th * th * s * s;
        float xy  = fs * mxy;
        float ch  = 1.0f + 2.0f * xy + y2;
        float cy  = 1.0f - x2;
        float inv = 1.0f / fmaxf(1.0f + 2.0f * xy + x2 * y2, MIN_NORM);
        float alpha = ch * fs * inv;
        float beta  = cy * inv;
        float gss = alpha * alpha * mx2 + 2.0f * alpha * beta * mxy + beta * beta * y2;
        float gn  = fmaxf(sqrtf(gss), MIN_NORM);
        float s2  = (gn > MAXNORM) ? (MAXNORM / gn) : 1.0f;
        float pn  = fmaxf(gn * s2, MIN_NORM);
        float lf  = artanh_clip(pn) / pn;
        Arow[t] = lf * s2 * alpha;
        Brow[t] = lf * s2 * beta;
    }
    __syncthreads();

    // ---- pass 1: per-row max |xt| over this wave's 64 cols, then block ----
    {
        float vmax[4];
        #pragma unroll
        for (int i = 0; i < 4; ++i) {
            const int rr = rh * 16 + q * 4 + i;
            float A = Arow[rr], B = Brow[rr];
            float m = 0.f;
            #pragma unroll
            for (int ct = 0; ct < 4; ++ct)
                m = fmaxf(m, fabsf(fmaf(A, acc[ct][i], B * yv[ct])));
            #pragma unroll
            for (int mk = 1; mk <= 8; mk <<= 1)
                m = fmaxf(m, __shfl_xor(m, mk, 64));
            vmax[i] = m;
        }
        if (lm == 0) {
            #pragma unroll
            for (int i = 0; i < 4; ++i) pmax[rh * 16 + q * 4 + i][wc] = vmax[i];
        }
    }
    __syncthreads();
    if (t < 32) {
        float rm = fmaxf(fmaxf(pmax[t][0], pmax[t][1]),
                         fmaxf(pmax[t][2], pmax[t][3]));
        Srow[t] = 127.0f / fmaxf(rm, 1e-30f);
        if (r0 + t < N) SCg[r0 + t] = rm * (1.0f / 127.0f);
    }
    __syncthreads();

    // ---- pass 2: encode (rint(xt*S)+128) into LDS staging, coalesced out ----
    #pragma unroll
    for (int i = 0; i < 4; ++i) {
        const int rr = rh * 16 + q * 4 + i;
        float A = Arow[rr], B = Brow[rr], S = Srow[rr];
        #pragma unroll
        for (int ct = 0; ct < 4; ++ct) {
            float v = fmaf(A, acc[ct][i], B * yv[ct]) * S;   // in [-127, 127]
            v = fminf(fmaxf(v, -127.0f), 127.0f);
            int qi = (int)rintf(v) + 128;                    // [1, 255]
            stage[rr * 256 + 64 * wc + ct * 16 + lm] = (unsigned char)qi;
        }
    }
    __syncthreads();
    {
        const int rr2 = t >> 4, seg = t & 15;   // 16 B per thread, 32 rows
        if (r0 + rr2 < N)
            *(uint4*)(XT8 + (size_t)(r0 + rr2) * 256 + seg * 16) =
                *(const uint4*)&stage[rr2 * 256 + seg * 16];
    }
}

// ---------------------------------------------------------------------------
// Kernel 3: sparse aggregation (int8 gather, fp32 accum) + HypAct.
// R3 gather structure (1 dword gather per edge = 2 cache lines); epilogue
// uses algebraic norm folding (||h|| = f*||acc||, ||o|| = f2*||tt||) so only
// 2 wave reductions remain (verified in R1).
// ---------------------------------------------------------------------------
__global__ __launch_bounds__(256) void agg_kernel(
    const int* __restrict__ rowptr, const int* __restrict__ cols,
    const float* __restrict__ vals, const float* __restrict__ SCg,
    const unsigned int* __restrict__ XT8u,
    float* __restrict__ OUT, int N)
{
    int node = (int)((blockIdx.x * (size_t)blockDim.x + threadIdx.x) >> 6);
    int l = threadIdx.x & 63;
    if (node >= N) return;

    int start = rowptr[node];
    int end   = rowptr[node + 1];

    float4 acc = make_float4(0.f, 0.f, 0.f, 0.f);
    float sw = 0.0f;   // sum of folded edge weights (identical across lanes)

    for (int base = start; base < end; base += 64) {
        int idx = base + l;
        bool ok = idx < end;
        int   myc = ok ? cols[idx] : 0;
        float myv = ok ? vals[idx] * SCg[myc] : 0.0f;   // fold dequant scale
        int cnt = min(64, end - base);
        int cnt16 = (cnt + 15) & ~15;   // pad to 16; padded lanes v=0, c=0 (hot line)

        for (int j = 0; j < cnt16; j += 16) {
            int   cc[16];
            float ww[16];
            #pragma unroll
            for (int u = 0; u < 16; ++u) {
                cc[u] = __shfl(myc, j + u, 64);
                ww[u] = __shfl(myv, j + u, 64);
            }
            unsigned int mw[16];
            #pragma unroll
            for (int u = 0; u < 16; ++u)
                mw[u] = XT8u[(size_t)cc[u] * 64 + l];   // 4 B/lane = 256 B row
            #pragma unroll
            for (int u = 0; u < 16; ++u) {
                float f0 = (float)( mw[u]        & 0xffu);   // v_cvt_f32_ubyte0
                float f1 = (float)((mw[u] >> 8)  & 0xffu);
                float f2 = (float)((mw[u] >> 16) & 0xffu);
                float f3 = (float)( mw[u] >> 24);
                acc.x = fmaf(ww[u], f0, acc.x);
                acc.y = fmaf(ww[u], f1, acc.y);
                acc.z = fmaf(ww[u], f2, acc.z);
                acc.w = fmaf(ww[u], f3, acc.w);
                sw += ww[u];
            }
        }
    }

    // exact -128 bias correction
    float corr = 128.0f * sw;
    acc.x -= corr; acc.y -= corr; acc.z -= corr; acc.w -= corr;

    // expmap0 + proj, norms folded algebraically
    float un = fmaxf(sqrtf(wave_reduce_sum(dot4(acc, acc))), MIN_NORM);
    float f  = tanhf(un) / un;
    float hn = f * un;                                // ||h|| before proj
    float s  = (hn > MAXNORM) ? (MAXNORM / hn) : 1.0f;
    // logmap0 + relu:  tt = relu(acc * f*s*lf)
    float pn = fmaxf(hn * s, MIN_NORM);
    float lf = artanh_clip(pn) / pn;
    float g  = f * s * lf;
    float4 tt = make_float4(fmaxf(acc.x * g, 0.f), fmaxf(acc.y * g, 0.f),
                            fmaxf(acc.z * g, 0.f), fmaxf(acc.w * g, 0.f));
    // expmap0 (c_out = 1) + proj
    float un2 = fmaxf(sqrtf(wave_reduce_sum(dot4(tt, tt))), MIN_NORM);
    float f2  = tanhf(un2) / un2;
    float on  = f2 * un2;                             // ||o|| before proj
    float s2  = (on > MAXNORM) ? (MAXNORM / on) : 1.0f;
    float fo  = f2 * s2;
    float4 o = make_float4(tt.x * fo, tt.y * fo, tt.z * fo, tt.w * fo);

    *(float4*)(OUT + (size_t)node * D + 4 * l) = o;
}

// ---------------------------------------------------------------------------
extern "C" void kernel_launch(void* const* d_in, const int* in_sizes, int n_in,
                              void* d_out, int out_size, void* d_ws, size_t ws_size,
                              hipStream_t stream) {
    const float* X    = (const float*)d_in[0];
    const float* W    = (const float*)d_in[1];
    const float* bias = (const float*)d_in[2];
    const float* vals = (const float*)d_in[3];
    const int*   rows = (const int*)d_in[4];
    const int*   cols = (const int*)d_in[5];
    float* OUT = (float*)d_out;

    const int N = in_sizes[0] / D;   // 10000
    const int E = in_sizes[3];       // 320000

    // ws layout (float units):
    //   rowptr [10240] | HB [512] | Wh [32768] | SCg [10240] | XT8 [...]
    int*           rowptr = (int*)d_ws;
    float*         HB  = (float*)d_ws + 10240;
    _Float16*      Wh  = (_Float16*)((float*)d_ws + 10240 + 512);
    float*         SCg = (float*)d_ws + 10240 + 512 + 32768;
    unsigned char* XT8 = (unsigned char*)((float*)d_ws + 10240 + 512 + 32768 + 10240);

    prep_kernel<<<(E + 255) / 256, 256, 0, stream>>>(bias, W, rows, HB, Wh, rowptr, N, E);
    gemmrow_kernel<<<(N + 31) / 32, 512, 0, stream>>>(X, Wh, HB, XT8, SCg, N);
    int wave_blocks = (N + 3) / 4;   // 4 waves per 256-thread block
    agg_kernel<<<wave_blocks, 256, 0, stream>>>(rowptr, cols, vals, SCg,
                                                (const unsigned int*)XT8, OUT, N);
}